// Round 11
// baseline (655.374 us; speedup 1.0000x reference)
//
#include <hip/hip_runtime.h>
#include <math.h>

// Problem constants (from reference setup_inputs)
constexpr int Bq = 32;
constexpr int Tq = 8192;
constexpr int Dq = 8;
constexpr int Qq = 8;
constexpr int Kq = 1024;
constexpr int NTOK = Bq * Tq;                         // 262144 tokens
constexpr float LOSS_SCALE = 0.25f / (float)(Bq * Tq * Dq);

// Round 11: 8 tokens/lane x 8 k-slices, scalar fp32, spill-proofed.
// R10 showed TLP is exhausted (16->32 waves/CU bought 5%): the wall is pipe
// DEMAND — LDS ~983K cy/CU, VALU ~852K cy/SIMD. LDS scales 1/Tk; Tk=8
// halves it to ~492K. R7's Tk=8 failed only via launch_bounds(256,4)'s
// 64-VGPR cap (compiler spilled ~50 regs -> +45MB scratch HBM).
// launch_bounds(256,2) lifts the cap to 256; state needs ~112 -> no spill,
// HW gives 4 waves/SIMD (512/128) and LDS gives 4 blocks/CU = 16 waves/CU —
// R6-level TLP, which R10 proved is enough.
// Geometry: wave = 8 slices x 8 subs; lane owns tokens tbase+8j (j=0..7),
// slice s scans k in [128s, 128s+128), owns token j==s.
// Skew (R7-proven): codeword float4 i -> i+(i>>8) (slice stride 257 f4);
// norms g -> g+((g>>7)<<2) (slice base 132s). d2 numerics bit-identical to
// every passing round: seq mul/fma dot, d2 = fmaf(dot,-2, rn+cn), strict '<'
// ascending k, lexicographic (d2,k) merge = np.argmin first-min.
__global__ __launch_bounds__(256, 2)
void rvq_main(const float* __restrict__ x,
              const float* __restrict__ codebooks,
              const float* __restrict__ post_scale,
              const float* __restrict__ post_bias,
              const float* __restrict__ conv_w,
              const float* __restrict__ conv_b,
              float* __restrict__ out)
{
    __shared__ __align__(16) float s_cb[8224];      // skewed codebook (32.1KB)
    __shared__ float s_cn[1056];                    // skewed norms (4.1KB)

    const int tid   = threadIdx.x;                 // 0..255
    const int lane  = tid & 63;
    const int wave  = tid >> 6;                    // 0..3
    const int slice = lane >> 3;                   // 0..7 -> k eighth
    const int sub   = lane & 7;                    // 0..7 -> token subgroup
    const int kbase = slice << 7;                  // 0,128,...,896
    const int tbase = blockIdx.x * 256 + wave * 64 + sub;  // + 8*j, j=0..7

    // residuals: 8 tokens per lane (duplicated across the 8 slices)
    float r[8][Dq];
#pragma unroll
    for (int j = 0; j < 8; ++j) {
        const float4* xp = reinterpret_cast<const float4*>(
            x + (size_t)(tbase + 8 * j) * Dq);
        float4 a = xp[0], b = xp[1];
        r[j][0]=a.x; r[j][1]=a.y; r[j][2]=a.z; r[j][3]=a.w;
        r[j][4]=b.x; r[j][5]=b.y; r[j][6]=b.z; r[j][7]=b.w;
    }

    // qsum only for the owned token (j == slice)
    float qso[Dq];
#pragma unroll
    for (int d = 0; d < Dq; ++d) qso[d] = 0.0f;
    float lossacc = 0.0f;

    float* out_quant = out;                               // [B*T*D]
    float* out_loss  = out + (size_t)NTOK * Dq;           // [1]
    float* out_codes = out_loss + 1;                      // [Q*B*T] as float

    for (int q = 0; q < Qq; ++q) {
        // ---- stage codebook q into LDS, skewed: float4 idx i -> i + (i>>8) ----
        {
            const float4* src = reinterpret_cast<const float4*>(
                codebooks + (size_t)q * Kq * Dq);
            float4* dst = reinterpret_cast<float4*>(s_cb);
#pragma unroll
            for (int it = 0; it < 8; ++it) {
                int i = tid + it * 256;
                dst[i + (i >> 8)] = src[i];
            }
        }
        __syncthreads();

        // ---- per-codeword squared norms (np order), skewed store ----
#pragma unroll
        for (int it = 0; it < 4; ++it) {
            int g = tid + it * 256;
            const float* c = s_cb + g * Dq + ((g >> 7) << 2);
            float n = __fmul_rn(c[0], c[0]);
#pragma unroll
            for (int d = 1; d < Dq; ++d)
                n = __fadd_rn(n, __fmul_rn(c[d], c[d]));
            s_cn[g + ((g >> 7) << 2)] = n;
        }
        __syncthreads();

        // ---- residual norms (np order) ----
        float rn[8];
#pragma unroll
        for (int j = 0; j < 8; ++j) {
            float n = __fmul_rn(r[j][0], r[j][0]);
#pragma unroll
            for (int d = 1; d < Dq; ++d)
                n = __fadd_rn(n, __fmul_rn(r[j][d], r[j][d]));
            rn[j] = n;
        }

        // ---- argmin over this slice's 128 codewords, 8 tokens per read ----
        float best[8];
        int   bk[8];
#pragma unroll
        for (int j = 0; j < 8; ++j) { best[j] = __builtin_inff(); bk[j] = kbase; }

        const float4* cb4 = reinterpret_cast<const float4*>(s_cb) + 257 * slice;
        const float*  cnp = s_cn + 132 * slice;
#pragma unroll 4
        for (int k = 0; k < Kq / 8; ++k) {
            float4 ca = cb4[2 * k];
            float4 cc = cb4[2 * k + 1];
            float cn = cnp[k];
            int cand = kbase + k;
#pragma unroll
            for (int j = 0; j < 8; ++j) {
                float dot = __fmul_rn(r[j][0], ca.x);
                dot = fmaf(r[j][1], ca.y, dot);
                dot = fmaf(r[j][2], ca.z, dot);
                dot = fmaf(r[j][3], ca.w, dot);
                dot = fmaf(r[j][4], cc.x, dot);
                dot = fmaf(r[j][5], cc.y, dot);
                dot = fmaf(r[j][6], cc.z, dot);
                dot = fmaf(r[j][7], cc.w, dot);
                float d2 = fmaf(dot, -2.0f, __fadd_rn(rn[j], cn));
                if (d2 < best[j]) { best[j] = d2; bk[j] = cand; }
            }
        }

        // ---- merge 8 slices: lexicographic (d2, k) min == np first-min ----
        int own_bk = 0;
#pragma unroll
        for (int j = 0; j < 8; ++j) {
            float b = best[j]; int k = bk[j];
#pragma unroll
            for (int m = 8; m <= 32; m <<= 1) {
                float ob = __shfl_xor(b, m, 64);
                int   ok = __shfl_xor(k, m, 64);
                if (ob < b || (ob == b && ok < k)) { b = ob; k = ok; }
            }
            bk[j] = k;
            if (j == slice) own_bk = k;
        }

        const float sc = post_scale[q];
        const float bi = post_bias[q];

        // codes: each lane owns token tbase+8*slice -> 64 distinct tokens/wave
        out_codes[(size_t)q * NTOK + tbase + 8 * slice] = (float)own_bk;

        // ---- update residuals (all 8 tokens); qsum/loss for owned only ----
#pragma unroll
        for (int j = 0; j < 8; ++j) {
            int kj = bk[j];
            const float* cc = s_cb + kj * Dq + ((kj >> 7) << 2);
#pragma unroll
            for (int d = 0; d < Dq; ++d) {
                float e = cc[d];
                float est = __fadd_rn(r[j][d], __fsub_rn(e, r[j][d]));
                if (j == slice)
                    qso[d] = __fadd_rn(__fadd_rn(qso[d], __fmul_rn(est, sc)), bi);
                float nr = __fsub_rn(r[j][d], e);
                float df = __fsub_rn(nr, e);
                if (j == slice) lossacc = fmaf(df, df, lossacc);
                r[j][d] = nr;
            }
        }
        __syncthreads();   // before next q overwrites s_cb
    }

    // ---- 1x1 conv epilogue: every lane writes its owned token ----
    {
        float o[Dq];
#pragma unroll
        for (int e = 0; e < Dq; ++e) {
            float acc = __fmul_rn(qso[0], conv_w[e * Dq + 0]);
#pragma unroll
            for (int d = 1; d < Dq; ++d)
                acc = fmaf(qso[d], conv_w[e * Dq + d], acc);
            o[e] = __fadd_rn(acc, conv_b[e]);
        }
        float4* op = reinterpret_cast<float4*>(
            out_quant + (size_t)(tbase + 8 * slice) * Dq);
        op[0] = make_float4(o[0], o[1], o[2], o[3]);
        op[1] = make_float4(o[4], o[5], o[6], o[7]);
    }

    // ---- loss reduction: each token counted once (its owner lane) ----
    float v = lossacc;
#pragma unroll
    for (int off = 32; off >= 1; off >>= 1)
        v += __shfl_xor(v, off, 64);
    if (lane == 0)
        atomicAdd(out_loss, v * LOSS_SCALE);
}

extern "C" void kernel_launch(void* const* d_in, const int* in_sizes, int n_in,
                              void* d_out, int out_size, void* d_ws, size_t ws_size,
                              hipStream_t stream) {
    const float* x     = (const float*)d_in[0];
    const float* cb    = (const float*)d_in[1];
    const float* ps    = (const float*)d_in[2];
    const float* pb    = (const float*)d_in[3];
    const float* cw    = (const float*)d_in[4];
    const float* cbias = (const float*)d_in[5];
    float* out = (float*)d_out;

    // zero the loss accumulator slot (d_out is poisoned before every call)
    hipMemsetAsync(out + (size_t)NTOK * Dq, 0, sizeof(float), stream);

    rvq_main<<<dim3(NTOK / 256), dim3(256), 0, stream>>>(
        x, cb, ps, pb, cw, cbias, out);
}

// Round 12
// 612.406 us; speedup vs baseline: 1.0702x; 1.0702x over previous
//
#include <hip/hip_runtime.h>
#include <math.h>

// Problem constants (from reference setup_inputs)
constexpr int Bq = 32;
constexpr int Tq = 8192;
constexpr int Dq = 8;
constexpr int Qq = 8;
constexpr int Kq = 1024;
constexpr int NTOK = Bq * Tq;                         // 262144 tokens
constexpr float LOSS_SCALE = 0.25f / (float)(Bq * Tq * Dq);

// Round 12: R10 (best, 614us: 512-thread blocks, 8 slices x 8 subs, Tk=4,
// VGPR=64, 32 waves/CU) + batched cn reads: one ds_read_b64 per 2 k instead
// of 2x ds_read_b32. LDS is the heavier pipe (983K cy/CU vs VALU 852K
// cy/SIMD); this cuts it ~9% with ZERO extra register pressure (the crux —
// R7/R9 showed what the 64-VGPR cap does to spilled state). Explicit 2-k
// body, no extra unroll, so the schedule stays R10-shaped.
// d2 numerics bit-identical to all passing rounds: seq mul/fma dot,
// d2 = fmaf(dot,-2, rn+cn), strict '<' ascending k, lex (d2,k) merge
// = np.argmin first-min. Skew: codeword float4 i -> i+(i>>8); norms
// g -> g+((g>>7)<<2) (slice base 132s, 8B-aligned for b64).
__global__ __launch_bounds__(512, 4)
void rvq_main(const float* __restrict__ x,
              const float* __restrict__ codebooks,
              const float* __restrict__ post_scale,
              const float* __restrict__ post_bias,
              const float* __restrict__ conv_w,
              const float* __restrict__ conv_b,
              float* __restrict__ out)
{
    __shared__ __align__(16) float s_cb[8224];      // skewed codebook (32.1KB)
    __shared__ __align__(16) float s_cn[1056];      // skewed norms (4.1KB)

    const int tid   = threadIdx.x;                 // 0..511
    const int lane  = tid & 63;
    const int wave  = tid >> 6;                    // 0..7
    const int slice = lane >> 3;                   // 0..7 -> k eighth
    const int sub   = lane & 7;                    // 0..7 -> token subgroup
    const int kbase = slice << 7;                  // 0,128,...,896
    const int tbase = blockIdx.x * 256 + wave * 32 + sub;  // + 8*j, j=0..3

    // residuals: 4 tokens per lane (tokens tbase+8j; duplicated across slices)
    float r[4][Dq];
#pragma unroll
    for (int j = 0; j < 4; ++j) {
        const float4* xp = reinterpret_cast<const float4*>(
            x + (size_t)(tbase + 8 * j) * Dq);
        float4 a = xp[0], b = xp[1];
        r[j][0]=a.x; r[j][1]=a.y; r[j][2]=a.z; r[j][3]=a.w;
        r[j][4]=b.x; r[j][5]=b.y; r[j][6]=b.z; r[j][7]=b.w;
    }

    // qsum only for the owned token (slices 0..3 own j == slice)
    float qso[Dq];
#pragma unroll
    for (int d = 0; d < Dq; ++d) qso[d] = 0.0f;
    float lossacc = 0.0f;

    float* out_quant = out;                               // [B*T*D]
    float* out_loss  = out + (size_t)NTOK * Dq;           // [1]
    float* out_codes = out_loss + 1;                      // [Q*B*T] as float

    for (int q = 0; q < Qq; ++q) {
        // ---- stage codebook q into LDS, skewed: float4 idx i -> i + (i>>8) ----
        {
            const float4* src = reinterpret_cast<const float4*>(
                codebooks + (size_t)q * Kq * Dq);
            float4* dst = reinterpret_cast<float4*>(s_cb);
#pragma unroll
            for (int it = 0; it < 4; ++it) {
                int i = tid + it * 512;
                dst[i + (i >> 8)] = src[i];
            }
        }
        __syncthreads();

        // ---- per-codeword squared norms (np order), skewed store ----
#pragma unroll
        for (int it = 0; it < 2; ++it) {
            int g = tid + it * 512;
            const float* c = s_cb + g * Dq + ((g >> 7) << 2);
            float n = __fmul_rn(c[0], c[0]);
#pragma unroll
            for (int d = 1; d < Dq; ++d)
                n = __fadd_rn(n, __fmul_rn(c[d], c[d]));
            s_cn[g + ((g >> 7) << 2)] = n;
        }
        __syncthreads();

        // ---- residual norms (np order) ----
        float rn[4];
#pragma unroll
        for (int j = 0; j < 4; ++j) {
            float n = __fmul_rn(r[j][0], r[j][0]);
#pragma unroll
            for (int d = 1; d < Dq; ++d)
                n = __fadd_rn(n, __fmul_rn(r[j][d], r[j][d]));
            rn[j] = n;
        }

        // ---- argmin over this slice's 128 codewords, 4 tokens per read ----
        float best[4];
        int   bk[4];
#pragma unroll
        for (int j = 0; j < 4; ++j) { best[j] = __builtin_inff(); bk[j] = kbase; }

        const float4* cb4 = reinterpret_cast<const float4*>(s_cb) + 257 * slice;
        const float2* cnp2 = reinterpret_cast<const float2*>(s_cn + 132 * slice);
#pragma unroll 1
        for (int k2 = 0; k2 < Kq / 16; ++k2) {      // 64 iters, 2 k each
            float2 cn2 = cnp2[k2];
#pragma unroll
            for (int kk = 0; kk < 2; ++kk) {
                const int k = 2 * k2 + kk;
                float4 ca = cb4[2 * k];
                float4 cc = cb4[2 * k + 1];
                float cn = (kk == 0) ? cn2.x : cn2.y;
                int cand = kbase + k;
#pragma unroll
                for (int j = 0; j < 4; ++j) {
                    float dot = __fmul_rn(r[j][0], ca.x);
                    dot = fmaf(r[j][1], ca.y, dot);
                    dot = fmaf(r[j][2], ca.z, dot);
                    dot = fmaf(r[j][3], ca.w, dot);
                    dot = fmaf(r[j][4], cc.x, dot);
                    dot = fmaf(r[j][5], cc.y, dot);
                    dot = fmaf(r[j][6], cc.z, dot);
                    dot = fmaf(r[j][7], cc.w, dot);
                    float d2 = fmaf(dot, -2.0f, __fadd_rn(rn[j], cn));
                    if (d2 < best[j]) { best[j] = d2; bk[j] = cand; }
                }
            }
        }

        // ---- merge 8 slices: lexicographic (d2, k) min == np first-min ----
        int own_bk = 0;
#pragma unroll
        for (int j = 0; j < 4; ++j) {
            float b = best[j]; int k = bk[j];
#pragma unroll
            for (int m = 8; m <= 32; m <<= 1) {
                float ob = __shfl_xor(b, m, 64);
                int   ok = __shfl_xor(k, m, 64);
                if (ob < b || (ob == b && ok < k)) { b = ob; k = ok; }
            }
            bk[j] = k;
            if (j == slice) own_bk = k;
        }

        const float sc = post_scale[q];
        const float bi = post_bias[q];

        // codes: slices 0..3 each own token tbase+8*slice -> contiguous 32/wave
        if (slice < 4)
            out_codes[(size_t)q * NTOK + tbase + 8 * slice] = (float)own_bk;

        // ---- update residuals (all 4 tokens); qsum/loss for owned only ----
#pragma unroll
        for (int j = 0; j < 4; ++j) {
            int kj = bk[j];
            const float* cc = s_cb + kj * Dq + ((kj >> 7) << 2);
#pragma unroll
            for (int d = 0; d < Dq; ++d) {
                float e = cc[d];
                float est = __fadd_rn(r[j][d], __fsub_rn(e, r[j][d]));
                if (j == slice)
                    qso[d] = __fadd_rn(__fadd_rn(qso[d], __fmul_rn(est, sc)), bi);
                float nr = __fsub_rn(r[j][d], e);
                float df = __fsub_rn(nr, e);
                if (j == slice) lossacc = fmaf(df, df, lossacc);
                r[j][d] = nr;
            }
        }
        __syncthreads();   // before next q overwrites s_cb
    }

    // ---- 1x1 conv epilogue: owning lanes (slice<4) write their token ----
    if (slice < 4) {
        float o[Dq];
#pragma unroll
        for (int e = 0; e < Dq; ++e) {
            float acc = __fmul_rn(qso[0], conv_w[e * Dq + 0]);
#pragma unroll
            for (int d = 1; d < Dq; ++d)
                acc = fmaf(qso[d], conv_w[e * Dq + d], acc);
            o[e] = __fadd_rn(acc, conv_b[e]);
        }
        float4* op = reinterpret_cast<float4*>(
            out_quant + (size_t)(tbase + 8 * slice) * Dq);
        op[0] = make_float4(o[0], o[1], o[2], o[3]);
        op[1] = make_float4(o[4], o[5], o[6], o[7]);
    }

    // ---- loss reduction: each token counted once (owner lanes) ----
    float v = lossacc;                              // slices 4..7 contribute 0
#pragma unroll
    for (int off = 32; off >= 1; off >>= 1)
        v += __shfl_xor(v, off, 64);
    if (lane == 0)
        atomicAdd(out_loss, v * LOSS_SCALE);
}

extern "C" void kernel_launch(void* const* d_in, const int* in_sizes, int n_in,
                              void* d_out, int out_size, void* d_ws, size_t ws_size,
                              hipStream_t stream) {
    const float* x     = (const float*)d_in[0];
    const float* cb    = (const float*)d_in[1];
    const float* ps    = (const float*)d_in[2];
    const float* pb    = (const float*)d_in[3];
    const float* cw    = (const float*)d_in[4];
    const float* cbias = (const float*)d_in[5];
    float* out = (float*)d_out;

    // zero the loss accumulator slot (d_out is poisoned before every call)
    hipMemsetAsync(out + (size_t)NTOK * Dq, 0, sizeof(float), stream);

    rvq_main<<<dim3(NTOK / 256), dim3(512), 0, stream>>>(
        x, cb, ps, pb, cw, cbias, out);
}